// Round 1
// baseline (236.653 us; speedup 1.0000x reference)
//
#include <hip/hip_runtime.h>
#include <hip/hip_bf16.h>

#define Bn 16
#define Sn 128
#define Hn 256
#define NLn 22
#define NSn 122

#define K2c 2.8853900817779268f   // 2*log2(e)
#define L2Ec 1.4426950408889634f  // log2(e)

#if __has_builtin(__builtin_amdgcn_exp2f)
__device__ __forceinline__ float fexp2(float x) { return __builtin_amdgcn_exp2f(x); }
#else
__device__ __forceinline__ float fexp2(float x) { return exp2f(x); }
#endif
#if __has_builtin(__builtin_amdgcn_rcpf)
__device__ __forceinline__ float frcp(float x) { return __builtin_amdgcn_rcpf(x); }
#else
__device__ __forceinline__ float frcp(float x) { return 1.0f / x; }
#endif

union F4 { float4 v; float f[4]; };

// ---------------------------------------------------------------------------
// k_hf: hf = h @ V2_ID_w + V2_ID_b (iteration-invariant), then store
//   Zr = exp2(clamp(-K2*hf))  and  Wz = w_ID * Zr.
// 8 rows per block, thread = output column.
// ---------------------------------------------------------------------------
__global__ __launch_bounds__(256) void k_hf(const float* __restrict__ hp,
                                            const float* __restrict__ V2w,
                                            const float* __restrict__ V2b,
                                            const float* __restrict__ wid,
                                            float* __restrict__ Zr,
                                            float* __restrict__ Wz) {
  __shared__ float xT[Hn][8];
  const int tid = threadIdx.x;
  const int r0 = blockIdx.x * 8;
  #pragma unroll
  for (int i = 0; i < 8; ++i) xT[tid][i] = hp[(size_t)(r0 + i) * Hn + tid];
  __syncthreads();

  float acc[8];
  const float bj = V2b[tid];
  #pragma unroll
  for (int i = 0; i < 8; ++i) acc[i] = bj;
  #pragma unroll 4
  for (int k = 0; k < Hn; ++k) {
    const float v = V2w[(size_t)k * Hn + tid];
    F4 xa, xb;
    xa.v = *(const float4*)&xT[k][0];
    xb.v = *(const float4*)&xT[k][4];
    acc[0] += xa.f[0] * v; acc[1] += xa.f[1] * v;
    acc[2] += xa.f[2] * v; acc[3] += xa.f[3] * v;
    acc[4] += xb.f[0] * v; acc[5] += xb.f[1] * v;
    acc[6] += xb.f[2] * v; acc[7] += xb.f[3] * v;
  }
  const float wv = wid[tid];
  #pragma unroll
  for (int i = 0; i < 8; ++i) {
    float z = -K2c * acc[i];
    z = fminf(fmaxf(z, -60.f), 60.f);
    const float zr = fexp2(z);
    Zr[(size_t)(r0 + i) * Hn + tid] = zr;
    Wz[(size_t)(r0 + i) * Hn + tid] = wv * zr;
  }
}

// ---------------------------------------------------------------------------
// k_A: per-b state update. If !first, first fold previous alphas:
//   r_inte = c_inte + g2_prev * (sum_s c_slot[s]*alpha[s])
// then m = r_inte @ W_SF; fsum = sum_s tanh(c_slot + m); g2 = fsum @ V_SF.
// tanh via fsum = S - 2*sum_s 1/(1+exp2(K2*x)).
// 16 blocks x 1024 threads; tid = (q<<8)|h, q = quarter for partial sums.
// ---------------------------------------------------------------------------
__global__ __launch_bounds__(1024) void k_A(const float* __restrict__ c_slot,
                                            const float* __restrict__ c_inte,
                                            const float* __restrict__ W_SF,
                                            const float* __restrict__ V_SF,
                                            const float* __restrict__ alphas,
                                            float* __restrict__ g2,
                                            int first) {
  __shared__ float rL[Hn];
  __shared__ float fL[Hn];
  __shared__ float pt[4 * Hn];
  __shared__ float aL[Sn];
  const int b = blockIdx.x;
  const int tid = threadIdx.x;
  const int h = tid & (Hn - 1);
  const int q = tid >> 8;

  if (!first) {
    if (tid < Sn) aL[tid] = alphas[b * Sn + tid];
    __syncthreads();
    float ps = 0.f;
    for (int s = q * 32; s < q * 32 + 32; ++s)
      ps += c_slot[(size_t)(b * Sn + s) * Hn + h] * aL[s];
    pt[q * Hn + h] = ps;
    __syncthreads();
    if (q == 0) {
      const float rsum = pt[h] + pt[Hn + h] + pt[2 * Hn + h] + pt[3 * Hn + h];
      rL[h] = c_inte[b * Hn + h] + g2[b * Hn + h] * rsum;
    }
  } else {
    if (q == 0) rL[h] = c_inte[b * Hn + h];
  }
  __syncthreads();

  // m[h] = sum_k rL[k] * W_SF[k][h], split over q
  float pm = 0.f;
  for (int k = q * 64; k < q * 64 + 64; ++k)
    pm += rL[k] * W_SF[(size_t)k * Hn + h];
  __syncthreads();               // protect pt from previous phase reads
  pt[q * Hn + h] = pm;
  __syncthreads();
  const float m = pt[h] + pt[Hn + h] + pt[2 * Hn + h] + pt[3 * Hn + h];

  // fsum partial: sum of 1/(1+e^{2x})
  float pr = 0.f;
  for (int s = q * 32; s < q * 32 + 32; ++s) {
    const float x = c_slot[(size_t)(b * Sn + s) * Hn + h] + m;
    const float e = fexp2(K2c * x);
    pr += frcp(e + 1.f);
  }
  __syncthreads();
  pt[q * Hn + h] = pr;
  __syncthreads();
  if (q == 0)
    fL[h] = (float)Sn - 2.f * (pt[h] + pt[Hn + h] + pt[2 * Hn + h] + pt[3 * Hn + h]);
  __syncthreads();

  // g2[h] = sum_k fL[k] * V_SF[k][h]
  float pg = 0.f;
  for (int k = q * 64; k < q * 64 + 64; ++k)
    pg += fL[k] * V_SF[(size_t)k * Hn + h];
  __syncthreads();
  pt[q * Hn + h] = pg;
  __syncthreads();
  if (q == 0)
    g2[b * Hn + h] = pt[h] + pt[Hn + h] + pt[2 * Hn + h] + pt[3 * Hn + h];
}

// ---------------------------------------------------------------------------
// k_C: per (b, 8-row group):
//   phase1: x[i][k] = g2[k]*c_slot[i][k]  -> LDS transposed
//   phase2: sf row-block = x @ V1_ID; Y = exp2(clamp(K2*sf)) -> LDS transposed
//   phase3: acc_ij = sum_h Wz[j][h] * rcp(Zr[j][h] + Y_i[h])   (j = thread)
//   phase4: scores_ij ~ -2*acc_ij (const offset cancels in softmax);
//           row softmax over j, emit only diagonal prob alpha[b, i0+i].
// ---------------------------------------------------------------------------
__global__ __launch_bounds__(256) void k_C(const float* __restrict__ c_slot,
                                           const float* __restrict__ V1,
                                           const float* __restrict__ g2,
                                           const float* __restrict__ Zr,
                                           const float* __restrict__ Wz,
                                           float* __restrict__ alphas) {
  __shared__ float xT[Hn][8];
  __shared__ float YT[Hn][8];
  __shared__ float sc[8][Sn];
  const int tid = threadIdx.x;
  const int b = blockIdx.x >> 4;
  const int i0 = (blockIdx.x & 15) * 8;

  // phase 1: stage x transposed
  {
    const float gv = g2[b * Hn + tid];
    #pragma unroll
    for (int i = 0; i < 8; ++i)
      xT[tid][i] = gv * c_slot[(size_t)(b * Sn + i0 + i) * Hn + tid];
  }
  __syncthreads();

  // phase 2: sf -> Y  (thread = column)
  {
    float acc[8];
    #pragma unroll
    for (int i = 0; i < 8; ++i) acc[i] = 0.f;
    #pragma unroll 4
    for (int k = 0; k < Hn; ++k) {
      const float v = V1[(size_t)k * Hn + tid];
      F4 xa, xb;
      xa.v = *(const float4*)&xT[k][0];
      xb.v = *(const float4*)&xT[k][4];
      acc[0] += xa.f[0] * v; acc[1] += xa.f[1] * v;
      acc[2] += xa.f[2] * v; acc[3] += xa.f[3] * v;
      acc[4] += xb.f[0] * v; acc[5] += xb.f[1] * v;
      acc[6] += xb.f[2] * v; acc[7] += xb.f[3] * v;
    }
    #pragma unroll
    for (int i = 0; i < 8; ++i) {
      float z = K2c * acc[i];
      z = fminf(fmaxf(z, -60.f), 60.f);
      YT[tid][i] = fexp2(z);
    }
  }
  __syncthreads();

  // phase 3: main rcp-einsum. thread -> (j, h-half)
  const int j = tid & (Sn - 1);
  const int hh = (tid >> 7) * (Hn / 2);
  float a8[8];
  #pragma unroll
  for (int i = 0; i < 8; ++i) a8[i] = 0.f;
  const float* zrp = Zr + (size_t)(b * Sn + j) * Hn + hh;
  const float* wzp = Wz + (size_t)(b * Sn + j) * Hn + hh;
  #pragma unroll 2
  for (int h4 = 0; h4 < Hn / 8; ++h4) {   // 32 iters x 4 h
    F4 zr4, wz4;
    zr4.v = *(const float4*)(zrp + h4 * 4);
    wz4.v = *(const float4*)(wzp + h4 * 4);
    #pragma unroll
    for (int e = 0; e < 4; ++e) {
      const int hx = hh + h4 * 4 + e;
      F4 ya, yb;
      ya.v = *(const float4*)&YT[hx][0];
      yb.v = *(const float4*)&YT[hx][4];
      const float z = zr4.f[e], w = wz4.f[e];
      a8[0] += w * frcp(z + ya.f[0]);
      a8[1] += w * frcp(z + ya.f[1]);
      a8[2] += w * frcp(z + ya.f[2]);
      a8[3] += w * frcp(z + ya.f[3]);
      a8[4] += w * frcp(z + yb.f[0]);
      a8[5] += w * frcp(z + yb.f[1]);
      a8[6] += w * frcp(z + yb.f[2]);
      a8[7] += w * frcp(z + yb.f[3]);
    }
  }

  // phase 4: combine halves, log2-domain scores, row softmax -> diag only
  if (tid >= Sn) {
    #pragma unroll
    for (int i = 0; i < 8; ++i) sc[i][j] = a8[i];
  }
  __syncthreads();
  if (tid < Sn) {
    #pragma unroll
    for (int i = 0; i < 8; ++i) {
      const float tot = a8[i] + sc[i][j];
      sc[i][j] = -2.f * L2Ec * tot;   // log2-scaled score (+const dropped)
    }
  }
  __syncthreads();

  const int row = tid >> 5;
  const int l5 = tid & 31;
  const float v0 = sc[row][l5];
  const float v1 = sc[row][l5 + 32];
  const float v2 = sc[row][l5 + 64];
  const float v3 = sc[row][l5 + 96];
  float mx = fmaxf(fmaxf(v0, v1), fmaxf(v2, v3));
  #pragma unroll
  for (int o = 16; o >= 1; o >>= 1) mx = fmaxf(mx, __shfl_xor(mx, o, 32));
  float sm = fexp2(v0 - mx) + fexp2(v1 - mx) + fexp2(v2 - mx) + fexp2(v3 - mx);
  #pragma unroll
  for (int o = 16; o >= 1; o >>= 1) sm += __shfl_xor(sm, o, 32);
  if (l5 == 0) {
    const int ig = i0 + row;
    const float d = sc[row][ig];
    alphas[b * Sn + ig] = fexp2(d - mx) * frcp(sm);
  }
}

// ---------------------------------------------------------------------------
// k_out1: r_inte_final = c_inte + g2*(sum_s c_slot*alpha); then
//   intent = [r_inte_final | h[:,S-1,:]] @ W_inte_ans
// ---------------------------------------------------------------------------
__global__ __launch_bounds__(256) void k_out1(const float* __restrict__ hp,
                                              const float* __restrict__ c_slot,
                                              const float* __restrict__ c_inte,
                                              const float* __restrict__ g2,
                                              const float* __restrict__ alphas,
                                              const float* __restrict__ Wi,
                                              float* __restrict__ outI) {
  __shared__ float aL[Sn];
  __shared__ float cv[2 * Hn];
  __shared__ float ip[NLn][8];
  const int b = blockIdx.x;
  const int tid = threadIdx.x;
  if (tid < Sn) aL[tid] = alphas[b * Sn + tid];
  __syncthreads();
  float rs = 0.f;
  for (int s = 0; s < Sn; ++s)
    rs += c_slot[(size_t)(b * Sn + s) * Hn + tid] * aL[s];
  cv[tid] = c_inte[b * Hn + tid] + g2[b * Hn + tid] * rs;
  cv[Hn + tid] = hp[(size_t)(b * Sn + Sn - 1) * Hn + tid];
  __syncthreads();
  if (tid < NLn * 8) {
    const int l = tid >> 3, c = tid & 7;
    float p = 0.f;
    for (int k = c * 64; k < c * 64 + 64; ++k) p += cv[k] * Wi[k * NLn + l];
    ip[l][c] = p;
  }
  __syncthreads();
  if (tid < NLn) {
    float t = 0.f;
    #pragma unroll
    for (int c = 0; c < 8; ++c) t += ip[tid][c];
    outI[b * NLn + tid] = t;
  }
}

// ---------------------------------------------------------------------------
// k_out2: slot = [h | g2*c_slot] @ W_slot_ans.  8 rows/block; thread =
// (col, k-half); cross-half reduce through LDS.
// ---------------------------------------------------------------------------
__global__ __launch_bounds__(256) void k_out2(const float* __restrict__ hp,
                                              const float* __restrict__ c_slot,
                                              const float* __restrict__ g2,
                                              const float* __restrict__ Ws,
                                              float* __restrict__ outS) {
  __shared__ float xT[2 * Hn][8];
  __shared__ float pp[8][128];
  const int tid = threadIdx.x;
  const int r0 = blockIdx.x * 8;
  const int b = r0 / Sn;
  {
    const float gv = g2[b * Hn + tid];
    #pragma unroll
    for (int i = 0; i < 8; ++i) {
      xT[tid][i] = hp[(size_t)(r0 + i) * Hn + tid];
      xT[Hn + tid][i] = gv * c_slot[(size_t)(r0 + i) * Hn + tid];
    }
  }
  __syncthreads();
  const int jc = tid & 127;
  const int kh = tid >> 7;
  float acc[8];
  #pragma unroll
  for (int i = 0; i < 8; ++i) acc[i] = 0.f;
  if (jc < NSn) {
    for (int k = kh * Hn; k < kh * Hn + Hn; ++k) {
      const float v = Ws[(size_t)k * NSn + jc];
      F4 xa, xb;
      xa.v = *(const float4*)&xT[k][0];
      xb.v = *(const float4*)&xT[k][4];
      acc[0] += xa.f[0] * v; acc[1] += xa.f[1] * v;
      acc[2] += xa.f[2] * v; acc[3] += xa.f[3] * v;
      acc[4] += xb.f[0] * v; acc[5] += xb.f[1] * v;
      acc[6] += xb.f[2] * v; acc[7] += xb.f[3] * v;
    }
  }
  if (kh == 1) {
    #pragma unroll
    for (int i = 0; i < 8; ++i) pp[i][jc] = acc[i];
  }
  __syncthreads();
  if (kh == 0 && jc < NSn) {
    #pragma unroll
    for (int i = 0; i < 8; ++i)
      outS[(size_t)(r0 + i) * NSn + jc] = acc[i] + pp[i][jc];
  }
}

// ---------------------------------------------------------------------------
extern "C" void kernel_launch(void* const* d_in, const int* in_sizes, int n_in,
                              void* d_out, int out_size, void* d_ws, size_t ws_size,
                              hipStream_t stream) {
  const float* hp     = (const float*)d_in[0];
  const float* c_slot = (const float*)d_in[1];
  const float* c_inte = (const float*)d_in[2];
  const float* W_SF   = (const float*)d_in[3];
  const float* V_SF   = (const float*)d_in[4];
  const float* V1     = (const float*)d_in[5];
  const float* V2w    = (const float*)d_in[6];
  const float* V2b    = (const float*)d_in[7];
  const float* wid    = (const float*)d_in[8];
  const float* Wi     = (const float*)d_in[9];
  const float* Ws     = (const float*)d_in[10];
  float* outS = (float*)d_out;                   // B*S*NS
  float* outI = (float*)d_out + Bn * Sn * NSn;   // B*NL

  float* ws = (float*)d_ws;
  float* Zr     = ws;                       // B*S*H
  float* Wz     = Zr + Bn * Sn * Hn;        // B*S*H
  float* g2     = Wz + Bn * Sn * Hn;        // B*H
  float* alphas = g2 + Bn * Hn;             // B*S

  hipLaunchKernelGGL(k_hf, dim3(Bn * Sn / 8), dim3(256), 0, stream,
                     hp, V2w, V2b, wid, Zr, Wz);
  for (int it = 0; it < 3; ++it) {
    hipLaunchKernelGGL(k_A, dim3(Bn), dim3(1024), 0, stream,
                       c_slot, c_inte, W_SF, V_SF, alphas, g2, it == 0 ? 1 : 0);
    hipLaunchKernelGGL(k_C, dim3(Bn * Sn / 8), dim3(256), 0, stream,
                       c_slot, V1, g2, Zr, Wz, alphas);
  }
  hipLaunchKernelGGL(k_out1, dim3(Bn), dim3(256), 0, stream,
                     hp, c_slot, c_inte, g2, alphas, Wi, outI);
  hipLaunchKernelGGL(k_out2, dim3(Bn * Sn / 8), dim3(256), 0, stream,
                     hp, c_slot, g2, Ws, outS);
}

// Round 2
// 211.931 us; speedup vs baseline: 1.1167x; 1.1167x over previous
//
#include <hip/hip_runtime.h>
#include <hip/hip_bf16.h>

#define Bn 16
#define Sn 128
#define Hn 256
#define NLn 22
#define NSn 122

#define K2c 2.8853900817779268f   // 2*log2(e)
#define L2Ec 1.4426950408889634f  // log2(e)

#if __has_builtin(__builtin_amdgcn_exp2f)
__device__ __forceinline__ float fexp2(float x) { return __builtin_amdgcn_exp2f(x); }
#else
__device__ __forceinline__ float fexp2(float x) { return exp2f(x); }
#endif
#if __has_builtin(__builtin_amdgcn_rcpf)
__device__ __forceinline__ float frcp(float x) { return __builtin_amdgcn_rcpf(x); }
#else
__device__ __forceinline__ float frcp(float x) { return 1.0f / x; }
#endif

union F4 { float4 v; float f[4]; };

// ---------------------------------------------------------------------------
// k_hf: hf = h @ V2_ID_w + V2_ID_b (iteration-invariant), then store
//   Zr = exp2(clamp(-K2*hf))  and  Wz = w_ID * Zr.
// 4 rows/block, 512 threads = col(256) x k-half(2). 512 blocks.
// ---------------------------------------------------------------------------
__global__ __launch_bounds__(512) void k_hf(const float* __restrict__ hp,
                                            const float* __restrict__ V2w,
                                            const float* __restrict__ V2b,
                                            const float* __restrict__ wid,
                                            float* __restrict__ Zr,
                                            float* __restrict__ Wz) {
  __shared__ float xT[Hn][4];
  __shared__ float pp[Hn][4];
  const int tid = threadIdx.x;
  const int r0 = blockIdx.x * 4;
  if (tid < Hn) {
    #pragma unroll
    for (int i = 0; i < 4; ++i) xT[tid][i] = hp[(size_t)(r0 + i) * Hn + tid];
  }
  __syncthreads();

  const int c = tid & (Hn - 1);
  const int kh = tid >> 8;
  float acc[4] = {0.f, 0.f, 0.f, 0.f};
  #pragma unroll 4
  for (int k = kh * 128; k < kh * 128 + 128; ++k) {
    const float v = V2w[(size_t)k * Hn + c];
    F4 xa; xa.v = *(const float4*)&xT[k][0];
    acc[0] += xa.f[0] * v; acc[1] += xa.f[1] * v;
    acc[2] += xa.f[2] * v; acc[3] += xa.f[3] * v;
  }
  if (kh) {
    F4 st; st.f[0] = acc[0]; st.f[1] = acc[1]; st.f[2] = acc[2]; st.f[3] = acc[3];
    *(float4*)&pp[c][0] = st.v;
  }
  __syncthreads();
  if (!kh) {
    const float bj = V2b[c];
    const float wv = wid[c];
    #pragma unroll
    for (int i = 0; i < 4; ++i) {
      float z = -K2c * (acc[i] + pp[c][i] + bj);
      z = fminf(fmaxf(z, -60.f), 60.f);
      const float zr = fexp2(z);
      Zr[(size_t)(r0 + i) * Hn + c] = zr;
      Wz[(size_t)(r0 + i) * Hn + c] = wv * zr;
    }
  }
}

// ---------------------------------------------------------------------------
// k_A: per-b state update (unchanged from R1).
// ---------------------------------------------------------------------------
__global__ __launch_bounds__(1024) void k_A(const float* __restrict__ c_slot,
                                            const float* __restrict__ c_inte,
                                            const float* __restrict__ W_SF,
                                            const float* __restrict__ V_SF,
                                            const float* __restrict__ alphas,
                                            float* __restrict__ g2,
                                            int first) {
  __shared__ float rL[Hn];
  __shared__ float fL[Hn];
  __shared__ float pt[4 * Hn];
  __shared__ float aL[Sn];
  const int b = blockIdx.x;
  const int tid = threadIdx.x;
  const int h = tid & (Hn - 1);
  const int q = tid >> 8;

  if (!first) {
    if (tid < Sn) aL[tid] = alphas[b * Sn + tid];
    __syncthreads();
    float ps = 0.f;
    for (int s = q * 32; s < q * 32 + 32; ++s)
      ps += c_slot[(size_t)(b * Sn + s) * Hn + h] * aL[s];
    pt[q * Hn + h] = ps;
    __syncthreads();
    if (q == 0) {
      const float rsum = pt[h] + pt[Hn + h] + pt[2 * Hn + h] + pt[3 * Hn + h];
      rL[h] = c_inte[b * Hn + h] + g2[b * Hn + h] * rsum;
    }
  } else {
    if (q == 0) rL[h] = c_inte[b * Hn + h];
  }
  __syncthreads();

  float pm = 0.f;
  for (int k = q * 64; k < q * 64 + 64; ++k)
    pm += rL[k] * W_SF[(size_t)k * Hn + h];
  __syncthreads();
  pt[q * Hn + h] = pm;
  __syncthreads();
  const float m = pt[h] + pt[Hn + h] + pt[2 * Hn + h] + pt[3 * Hn + h];

  float pr = 0.f;
  for (int s = q * 32; s < q * 32 + 32; ++s) {
    const float x = c_slot[(size_t)(b * Sn + s) * Hn + h] + m;
    const float e = fexp2(K2c * x);
    pr += frcp(e + 1.f);
  }
  __syncthreads();
  pt[q * Hn + h] = pr;
  __syncthreads();
  if (q == 0)
    fL[h] = (float)Sn - 2.f * (pt[h] + pt[Hn + h] + pt[2 * Hn + h] + pt[3 * Hn + h]);
  __syncthreads();

  float pg = 0.f;
  for (int k = q * 64; k < q * 64 + 64; ++k)
    pg += fL[k] * V_SF[(size_t)k * Hn + h];
  __syncthreads();
  pt[q * Hn + h] = pg;
  __syncthreads();
  if (q == 0)
    g2[b * Hn + h] = pt[h] + pt[Hn + h] + pt[2 * Hn + h] + pt[3 * Hn + h];
}

// ---------------------------------------------------------------------------
// k_C: per (b, 4-row group), 512 threads = j(128) x h-quarter(4). 512 blocks.
//   phase1: x[i][k] = g2[k]*c_slot[i][k]  -> LDS transposed
//   phase2: sf = x @ V1 (col x k-half split); Y = exp2(clamp(K2*sf)) -> LDS
//   phase3: partial acc_ij = sum_{h in quarter} Wz[j][h]*rcp(Zr[j][h]+Y_i[h])
//   phase4: cross-quarter LDS reduce; row softmax over j; emit diag alpha.
// ---------------------------------------------------------------------------
__global__ __launch_bounds__(512) void k_C(const float* __restrict__ c_slot,
                                           const float* __restrict__ V1,
                                           const float* __restrict__ g2,
                                           const float* __restrict__ Zr,
                                           const float* __restrict__ Wz,
                                           float* __restrict__ alphas) {
  __shared__ float xT[Hn][4];
  __shared__ float YT[Hn][4];
  __shared__ float pp[Hn][4];
  __shared__ float red[3][4][Sn];
  __shared__ float sc[4][Sn];
  const int tid = threadIdx.x;
  const int b = blockIdx.x >> 5;
  const int i0 = (blockIdx.x & 31) * 4;

  // phase 1
  if (tid < Hn) {
    const float gv = g2[b * Hn + tid];
    #pragma unroll
    for (int i = 0; i < 4; ++i)
      xT[tid][i] = gv * c_slot[(size_t)(b * Sn + i0 + i) * Hn + tid];
  }
  __syncthreads();

  // phase 2
  {
    const int c = tid & (Hn - 1);
    const int kh = tid >> 8;
    float acc[4] = {0.f, 0.f, 0.f, 0.f};
    #pragma unroll 4
    for (int k = kh * 128; k < kh * 128 + 128; ++k) {
      const float v = V1[(size_t)k * Hn + c];
      F4 xa; xa.v = *(const float4*)&xT[k][0];
      acc[0] += xa.f[0] * v; acc[1] += xa.f[1] * v;
      acc[2] += xa.f[2] * v; acc[3] += xa.f[3] * v;
    }
    if (kh) {
      F4 st; st.f[0] = acc[0]; st.f[1] = acc[1]; st.f[2] = acc[2]; st.f[3] = acc[3];
      *(float4*)&pp[c][0] = st.v;
    }
    __syncthreads();
    if (!kh) {
      #pragma unroll
      for (int i = 0; i < 4; ++i) {
        float z = K2c * (acc[i] + pp[c][i]);
        z = fminf(fmaxf(z, -60.f), 60.f);
        YT[c][i] = fexp2(z);
      }
    }
  }
  __syncthreads();

  // phase 3
  const int j = tid & (Sn - 1);
  const int hq = tid >> 7;
  float a4[4] = {0.f, 0.f, 0.f, 0.f};
  const float* zrp = Zr + (size_t)(b * Sn + j) * Hn + hq * 64;
  const float* wzp = Wz + (size_t)(b * Sn + j) * Hn + hq * 64;
  #pragma unroll 4
  for (int h4 = 0; h4 < 16; ++h4) {
    F4 zr4, wz4;
    zr4.v = *(const float4*)(zrp + h4 * 4);
    wz4.v = *(const float4*)(wzp + h4 * 4);
    #pragma unroll
    for (int e = 0; e < 4; ++e) {
      const int hx = hq * 64 + h4 * 4 + e;
      F4 ya; ya.v = *(const float4*)&YT[hx][0];
      const float z = zr4.f[e], w = wz4.f[e];
      a4[0] += w * frcp(z + ya.f[0]);
      a4[1] += w * frcp(z + ya.f[1]);
      a4[2] += w * frcp(z + ya.f[2]);
      a4[3] += w * frcp(z + ya.f[3]);
    }
  }
  if (hq) {
    #pragma unroll
    for (int i = 0; i < 4; ++i) red[hq - 1][i][j] = a4[i];
  }
  __syncthreads();
  if (!hq) {
    #pragma unroll
    for (int i = 0; i < 4; ++i) {
      const float tot = a4[i] + red[0][i][j] + red[1][i][j] + red[2][i][j];
      sc[i][j] = -2.f * L2Ec * tot;   // log2-scaled score (const offset dropped)
    }
  }
  __syncthreads();

  // phase 4: softmax (4 rows x 32 lanes)
  if (tid < 128) {
    const int row = tid >> 5;
    const int l5 = tid & 31;
    const float v0 = sc[row][l5];
    const float v1 = sc[row][l5 + 32];
    const float v2 = sc[row][l5 + 64];
    const float v3 = sc[row][l5 + 96];
    float mx = fmaxf(fmaxf(v0, v1), fmaxf(v2, v3));
    #pragma unroll
    for (int o = 16; o >= 1; o >>= 1) mx = fmaxf(mx, __shfl_xor(mx, o, 32));
    float sm = fexp2(v0 - mx) + fexp2(v1 - mx) + fexp2(v2 - mx) + fexp2(v3 - mx);
    #pragma unroll
    for (int o = 16; o >= 1; o >>= 1) sm += __shfl_xor(sm, o, 32);
    if (l5 == 0) {
      const int ig = i0 + row;
      const float d = sc[row][ig];
      alphas[b * Sn + ig] = fexp2(d - mx) * frcp(sm);
    }
  }
}

// ---------------------------------------------------------------------------
// k_out1: r_inte_final = c_inte + g2*(sum_s c_slot*alpha); then
//   intent = [r_inte_final | h[:,S-1,:]] @ W_inte_ans.  16 blocks x 1024 thr.
// ---------------------------------------------------------------------------
__global__ __launch_bounds__(1024) void k_out1(const float* __restrict__ hp,
                                               const float* __restrict__ c_slot,
                                               const float* __restrict__ c_inte,
                                               const float* __restrict__ g2,
                                               const float* __restrict__ alphas,
                                               const float* __restrict__ Wi,
                                               float* __restrict__ outI) {
  __shared__ float aL[Sn];
  __shared__ float cv[2 * Hn];
  __shared__ float pt[4][Hn];
  __shared__ float ip[NLn][16];
  const int b = blockIdx.x;
  const int tid = threadIdx.x;
  if (tid < Sn) aL[tid] = alphas[b * Sn + tid];
  __syncthreads();
  const int h = tid & (Hn - 1);
  const int q = tid >> 8;
  float ps = 0.f;
  for (int s = q * 32; s < q * 32 + 32; ++s)
    ps += c_slot[(size_t)(b * Sn + s) * Hn + h] * aL[s];
  pt[q][h] = ps;
  __syncthreads();
  if (q == 0) {
    cv[h] = c_inte[b * Hn + h] + g2[b * Hn + h] * (pt[0][h] + pt[1][h] + pt[2][h] + pt[3][h]);
    cv[Hn + h] = hp[(size_t)(b * Sn + Sn - 1) * Hn + h];
  }
  __syncthreads();
  if (tid < NLn * 16) {
    const int l = tid >> 4, c = tid & 15;
    float p = 0.f;
    for (int k = c * 32; k < c * 32 + 32; ++k) p += cv[k] * Wi[k * NLn + l];
    ip[l][c] = p;
  }
  __syncthreads();
  if (tid < NLn) {
    float t = 0.f;
    #pragma unroll
    for (int c = 0; c < 16; ++c) t += ip[tid][c];
    outI[b * NLn + tid] = t;
  }
}

// ---------------------------------------------------------------------------
// k_out2: slot = [h | g2*c_slot] @ W_slot_ans.  4 rows/block, 512 blocks,
// 512 threads = col(128) x k-quarter(4); cross-quarter reduce via LDS.
// ---------------------------------------------------------------------------
__global__ __launch_bounds__(512) void k_out2(const float* __restrict__ hp,
                                              const float* __restrict__ c_slot,
                                              const float* __restrict__ g2,
                                              const float* __restrict__ Ws,
                                              float* __restrict__ outS) {
  __shared__ float xT[2 * Hn][4];
  __shared__ float pp[3][4][128];
  const int tid = threadIdx.x;
  const int r0 = blockIdx.x * 4;
  const int b = r0 / Sn;
  if (tid < Hn) {
    #pragma unroll
    for (int i = 0; i < 4; ++i)
      xT[tid][i] = hp[(size_t)(r0 + i) * Hn + tid];
  } else {
    const int t = tid - Hn;
    const float gv = g2[b * Hn + t];
    #pragma unroll
    for (int i = 0; i < 4; ++i)
      xT[Hn + t][i] = gv * c_slot[(size_t)(r0 + i) * Hn + t];
  }
  __syncthreads();

  const int jc = tid & 127;
  const int kq = tid >> 7;
  float acc[4] = {0.f, 0.f, 0.f, 0.f};
  if (jc < NSn) {
    #pragma unroll 4
    for (int k = kq * 128; k < kq * 128 + 128; ++k) {
      const float v = Ws[(size_t)k * NSn + jc];
      F4 xa; xa.v = *(const float4*)&xT[k][0];
      acc[0] += xa.f[0] * v; acc[1] += xa.f[1] * v;
      acc[2] += xa.f[2] * v; acc[3] += xa.f[3] * v;
    }
  }
  if (kq) {
    #pragma unroll
    for (int i = 0; i < 4; ++i) pp[kq - 1][i][jc] = acc[i];
  }
  __syncthreads();
  if (!kq && jc < NSn) {
    #pragma unroll
    for (int i = 0; i < 4; ++i)
      outS[(size_t)(r0 + i) * NSn + jc] =
          acc[i] + pp[0][i][jc] + pp[1][i][jc] + pp[2][i][jc];
  }
}

// ---------------------------------------------------------------------------
extern "C" void kernel_launch(void* const* d_in, const int* in_sizes, int n_in,
                              void* d_out, int out_size, void* d_ws, size_t ws_size,
                              hipStream_t stream) {
  const float* hp     = (const float*)d_in[0];
  const float* c_slot = (const float*)d_in[1];
  const float* c_inte = (const float*)d_in[2];
  const float* W_SF   = (const float*)d_in[3];
  const float* V_SF   = (const float*)d_in[4];
  const float* V1     = (const float*)d_in[5];
  const float* V2w    = (const float*)d_in[6];
  const float* V2b    = (const float*)d_in[7];
  const float* wid    = (const float*)d_in[8];
  const float* Wi     = (const float*)d_in[9];
  const float* Ws     = (const float*)d_in[10];
  float* outS = (float*)d_out;                   // B*S*NS
  float* outI = (float*)d_out + Bn * Sn * NSn;   // B*NL

  float* ws = (float*)d_ws;
  float* Zr     = ws;                       // B*S*H
  float* Wz     = Zr + Bn * Sn * Hn;        // B*S*H
  float* g2     = Wz + Bn * Sn * Hn;        // B*H
  float* alphas = g2 + Bn * Hn;             // B*S

  hipLaunchKernelGGL(k_hf, dim3(Bn * Sn / 4), dim3(512), 0, stream,
                     hp, V2w, V2b, wid, Zr, Wz);
  for (int it = 0; it < 3; ++it) {
    hipLaunchKernelGGL(k_A, dim3(Bn), dim3(1024), 0, stream,
                       c_slot, c_inte, W_SF, V_SF, alphas, g2, it == 0 ? 1 : 0);
    hipLaunchKernelGGL(k_C, dim3(Bn * Sn / 4), dim3(512), 0, stream,
                       c_slot, V1, g2, Zr, Wz, alphas);
  }
  hipLaunchKernelGGL(k_out1, dim3(Bn), dim3(1024), 0, stream,
                     hp, c_slot, c_inte, g2, alphas, Wi, outI);
  hipLaunchKernelGGL(k_out2, dim3(Bn * Sn / 4), dim3(512), 0, stream,
                     hp, c_slot, g2, Ws, outS);
}

// Round 3
// 186.356 us; speedup vs baseline: 1.2699x; 1.1372x over previous
//
#include <hip/hip_runtime.h>
#include <hip/hip_bf16.h>

#define Bn 16
#define Sn 128
#define Hn 256
#define NLn 22
#define NSn 122

#define K2c 2.8853900817779268f   // 2*log2(e)
#define L2Ec 1.4426950408889634f  // log2(e)

#if __has_builtin(__builtin_amdgcn_exp2f)
__device__ __forceinline__ float fexp2(float x) { return __builtin_amdgcn_exp2f(x); }
#else
__device__ __forceinline__ float fexp2(float x) { return exp2f(x); }
#endif
#if __has_builtin(__builtin_amdgcn_rcpf)
__device__ __forceinline__ float frcp(float x) { return __builtin_amdgcn_rcpf(x); }
#else
__device__ __forceinline__ float frcp(float x) { return 1.0f / x; }
#endif

union F4 { float4 v; float f[4]; };

// ---------------------------------------------------------------------------
// k_hf: hf = h @ V2_ID_w + V2_ID_b (iteration-invariant), then store
//   ZrT[b][h][j] = exp2(clamp(-K2*hf[j,h]))  and  WzT = w_ID[h] * ZrT
// TRANSPOSED (j-contiguous) so k_C phase-3 loads are wave-coalesced.
// 4 rows/block, 512 threads = col(256) x k-half(2). 512 blocks.
// ---------------------------------------------------------------------------
__global__ __launch_bounds__(512) void k_hf(const float* __restrict__ hp,
                                            const float* __restrict__ V2w,
                                            const float* __restrict__ V2b,
                                            const float* __restrict__ wid,
                                            float* __restrict__ ZrT,
                                            float* __restrict__ WzT) {
  __shared__ float xT[Hn][4];
  __shared__ float pp[Hn][4];
  const int tid = threadIdx.x;
  const int r0 = blockIdx.x * 4;
  const int b = r0 >> 7;          // r0 / Sn
  const int j0 = r0 & (Sn - 1);   // r0 % Sn
  if (tid < Hn) {
    #pragma unroll
    for (int i = 0; i < 4; ++i) xT[tid][i] = hp[(size_t)(r0 + i) * Hn + tid];
  }
  __syncthreads();

  const int c = tid & (Hn - 1);
  const int kh = tid >> 8;
  float acc[4] = {0.f, 0.f, 0.f, 0.f};
  #pragma unroll 4
  for (int k = kh * 128; k < kh * 128 + 128; ++k) {
    const float v = V2w[(size_t)k * Hn + c];
    F4 xa; xa.v = *(const float4*)&xT[k][0];
    acc[0] += xa.f[0] * v; acc[1] += xa.f[1] * v;
    acc[2] += xa.f[2] * v; acc[3] += xa.f[3] * v;
  }
  if (kh) {
    F4 st; st.f[0] = acc[0]; st.f[1] = acc[1]; st.f[2] = acc[2]; st.f[3] = acc[3];
    *(float4*)&pp[c][0] = st.v;
  }
  __syncthreads();
  if (!kh) {
    const float bj = V2b[c];
    const float wv = wid[c];
    #pragma unroll
    for (int i = 0; i < 4; ++i) {
      float z = -K2c * (acc[i] + pp[c][i] + bj);
      z = fminf(fmaxf(z, -60.f), 60.f);
      const float zr = fexp2(z);
      ZrT[((size_t)b * Hn + c) * Sn + j0 + i] = zr;
      WzT[((size_t)b * Hn + c) * Sn + j0 + i] = wv * zr;
    }
  }
}

// ---------------------------------------------------------------------------
// k_A: per-b state update (unchanged).
// ---------------------------------------------------------------------------
__global__ __launch_bounds__(1024) void k_A(const float* __restrict__ c_slot,
                                            const float* __restrict__ c_inte,
                                            const float* __restrict__ W_SF,
                                            const float* __restrict__ V_SF,
                                            const float* __restrict__ alphas,
                                            float* __restrict__ g2,
                                            int first) {
  __shared__ float rL[Hn];
  __shared__ float fL[Hn];
  __shared__ float pt[4 * Hn];
  __shared__ float aL[Sn];
  const int b = blockIdx.x;
  const int tid = threadIdx.x;
  const int h = tid & (Hn - 1);
  const int q = tid >> 8;

  if (!first) {
    if (tid < Sn) aL[tid] = alphas[b * Sn + tid];
    __syncthreads();
    float ps = 0.f;
    for (int s = q * 32; s < q * 32 + 32; ++s)
      ps += c_slot[(size_t)(b * Sn + s) * Hn + h] * aL[s];
    pt[q * Hn + h] = ps;
    __syncthreads();
    if (q == 0) {
      const float rsum = pt[h] + pt[Hn + h] + pt[2 * Hn + h] + pt[3 * Hn + h];
      rL[h] = c_inte[b * Hn + h] + g2[b * Hn + h] * rsum;
    }
  } else {
    if (q == 0) rL[h] = c_inte[b * Hn + h];
  }
  __syncthreads();

  float pm = 0.f;
  for (int k = q * 64; k < q * 64 + 64; ++k)
    pm += rL[k] * W_SF[(size_t)k * Hn + h];
  __syncthreads();
  pt[q * Hn + h] = pm;
  __syncthreads();
  const float m = pt[h] + pt[Hn + h] + pt[2 * Hn + h] + pt[3 * Hn + h];

  float pr = 0.f;
  for (int s = q * 32; s < q * 32 + 32; ++s) {
    const float x = c_slot[(size_t)(b * Sn + s) * Hn + h] + m;
    const float e = fexp2(K2c * x);
    pr += frcp(e + 1.f);
  }
  __syncthreads();
  pt[q * Hn + h] = pr;
  __syncthreads();
  if (q == 0)
    fL[h] = (float)Sn - 2.f * (pt[h] + pt[Hn + h] + pt[2 * Hn + h] + pt[3 * Hn + h]);
  __syncthreads();

  float pg = 0.f;
  for (int k = q * 64; k < q * 64 + 64; ++k)
    pg += fL[k] * V_SF[(size_t)k * Hn + h];
  __syncthreads();
  pt[q * Hn + h] = pg;
  __syncthreads();
  if (q == 0)
    g2[b * Hn + h] = pt[h] + pt[Hn + h] + pt[2 * Hn + h] + pt[3 * Hn + h];
}

// ---------------------------------------------------------------------------
// k_C: per (b, 4-row group), 512 threads = j(128) x h-quarter(4). 512 blocks.
//   phase1: x[i][k] = g2[k]*c_slot[i][k]  -> LDS transposed
//   phase2: sf = x @ V1 (col x k-half split); Y = exp2(clamp(K2*sf)) -> LDS
//   phase3: partial acc_ij = sum_{h in quarter} WzT[h][j]*rcp(ZrT[h][j]+Y_i[h])
//           (ZrT/WzT are j-contiguous -> coalesced scalar loads, lane = j)
//   phase4: cross-quarter LDS reduce; row softmax over j; emit diag alpha.
// ---------------------------------------------------------------------------
__global__ __launch_bounds__(512) void k_C(const float* __restrict__ c_slot,
                                           const float* __restrict__ V1,
                                           const float* __restrict__ g2,
                                           const float* __restrict__ ZrT,
                                           const float* __restrict__ WzT,
                                           float* __restrict__ alphas) {
  __shared__ float xT[Hn][4];
  __shared__ float YT[Hn][4];
  __shared__ float pp[Hn][4];
  __shared__ float red[3][4][Sn];
  __shared__ float sc[4][Sn];
  const int tid = threadIdx.x;
  const int b = blockIdx.x >> 5;
  const int i0 = (blockIdx.x & 31) * 4;

  // phase 1
  if (tid < Hn) {
    const float gv = g2[b * Hn + tid];
    #pragma unroll
    for (int i = 0; i < 4; ++i)
      xT[tid][i] = gv * c_slot[(size_t)(b * Sn + i0 + i) * Hn + tid];
  }
  __syncthreads();

  // phase 2
  {
    const int c = tid & (Hn - 1);
    const int kh = tid >> 8;
    float acc[4] = {0.f, 0.f, 0.f, 0.f};
    #pragma unroll 4
    for (int k = kh * 128; k < kh * 128 + 128; ++k) {
      const float v = V1[(size_t)k * Hn + c];
      F4 xa; xa.v = *(const float4*)&xT[k][0];
      acc[0] += xa.f[0] * v; acc[1] += xa.f[1] * v;
      acc[2] += xa.f[2] * v; acc[3] += xa.f[3] * v;
    }
    if (kh) {
      F4 st; st.f[0] = acc[0]; st.f[1] = acc[1]; st.f[2] = acc[2]; st.f[3] = acc[3];
      *(float4*)&pp[c][0] = st.v;
    }
    __syncthreads();
    if (!kh) {
      #pragma unroll
      for (int i = 0; i < 4; ++i) {
        float z = K2c * (acc[i] + pp[c][i]);
        z = fminf(fmaxf(z, -60.f), 60.f);
        YT[c][i] = fexp2(z);
      }
    }
  }
  __syncthreads();

  // phase 3: coalesced (lane = j, contiguous in ZrT/WzT)
  const int j = tid & (Sn - 1);
  const int hq = tid >> 7;
  float a4[4] = {0.f, 0.f, 0.f, 0.f};
  const float* zrp = ZrT + ((size_t)b * Hn + hq * 64) * Sn + j;
  const float* wzp = WzT + ((size_t)b * Hn + hq * 64) * Sn + j;
  #pragma unroll 4
  for (int hh = 0; hh < 64; ++hh) {
    const float z = zrp[(size_t)hh * Sn];
    const float w = wzp[(size_t)hh * Sn];
    F4 ya; ya.v = *(const float4*)&YT[hq * 64 + hh][0];
    a4[0] += w * frcp(z + ya.f[0]);
    a4[1] += w * frcp(z + ya.f[1]);
    a4[2] += w * frcp(z + ya.f[2]);
    a4[3] += w * frcp(z + ya.f[3]);
  }
  if (hq) {
    #pragma unroll
    for (int i = 0; i < 4; ++i) red[hq - 1][i][j] = a4[i];
  }
  __syncthreads();
  if (!hq) {
    #pragma unroll
    for (int i = 0; i < 4; ++i) {
      const float tot = a4[i] + red[0][i][j] + red[1][i][j] + red[2][i][j];
      sc[i][j] = -2.f * L2Ec * tot;   // log2-scaled score (const offset dropped)
    }
  }
  __syncthreads();

  // phase 4: softmax (4 rows x 32 lanes)
  if (tid < 128) {
    const int row = tid >> 5;
    const int l5 = tid & 31;
    const float v0 = sc[row][l5];
    const float v1 = sc[row][l5 + 32];
    const float v2 = sc[row][l5 + 64];
    const float v3 = sc[row][l5 + 96];
    float mx = fmaxf(fmaxf(v0, v1), fmaxf(v2, v3));
    #pragma unroll
    for (int o = 16; o >= 1; o >>= 1) mx = fmaxf(mx, __shfl_xor(mx, o, 32));
    float sm = fexp2(v0 - mx) + fexp2(v1 - mx) + fexp2(v2 - mx) + fexp2(v3 - mx);
    #pragma unroll
    for (int o = 16; o >= 1; o >>= 1) sm += __shfl_xor(sm, o, 32);
    if (l5 == 0) {
      const int ig = i0 + row;
      const float d = sc[row][ig];
      alphas[b * Sn + ig] = fexp2(d - mx) * frcp(sm);
    }
  }
}

// ---------------------------------------------------------------------------
// k_out1 (unchanged): intent head.
// ---------------------------------------------------------------------------
__global__ __launch_bounds__(1024) void k_out1(const float* __restrict__ hp,
                                               const float* __restrict__ c_slot,
                                               const float* __restrict__ c_inte,
                                               const float* __restrict__ g2,
                                               const float* __restrict__ alphas,
                                               const float* __restrict__ Wi,
                                               float* __restrict__ outI) {
  __shared__ float aL[Sn];
  __shared__ float cv[2 * Hn];
  __shared__ float pt[4][Hn];
  __shared__ float ip[NLn][16];
  const int b = blockIdx.x;
  const int tid = threadIdx.x;
  if (tid < Sn) aL[tid] = alphas[b * Sn + tid];
  __syncthreads();
  const int h = tid & (Hn - 1);
  const int q = tid >> 8;
  float ps = 0.f;
  for (int s = q * 32; s < q * 32 + 32; ++s)
    ps += c_slot[(size_t)(b * Sn + s) * Hn + h] * aL[s];
  pt[q][h] = ps;
  __syncthreads();
  if (q == 0) {
    cv[h] = c_inte[b * Hn + h] + g2[b * Hn + h] * (pt[0][h] + pt[1][h] + pt[2][h] + pt[3][h]);
    cv[Hn + h] = hp[(size_t)(b * Sn + Sn - 1) * Hn + h];
  }
  __syncthreads();
  if (tid < NLn * 16) {
    const int l = tid >> 4, c = tid & 15;
    float p = 0.f;
    for (int k = c * 32; k < c * 32 + 32; ++k) p += cv[k] * Wi[k * NLn + l];
    ip[l][c] = p;
  }
  __syncthreads();
  if (tid < NLn) {
    float t = 0.f;
    #pragma unroll
    for (int c = 0; c < 16; ++c) t += ip[tid][c];
    outI[b * NLn + tid] = t;
  }
}

// ---------------------------------------------------------------------------
// k_out2 (unchanged): slot head.
// ---------------------------------------------------------------------------
__global__ __launch_bounds__(512) void k_out2(const float* __restrict__ hp,
                                              const float* __restrict__ c_slot,
                                              const float* __restrict__ g2,
                                              const float* __restrict__ Ws,
                                              float* __restrict__ outS) {
  __shared__ float xT[2 * Hn][4];
  __shared__ float pp[3][4][128];
  const int tid = threadIdx.x;
  const int r0 = blockIdx.x * 4;
  const int b = r0 / Sn;
  if (tid < Hn) {
    #pragma unroll
    for (int i = 0; i < 4; ++i)
      xT[tid][i] = hp[(size_t)(r0 + i) * Hn + tid];
  } else {
    const int t = tid - Hn;
    const float gv = g2[b * Hn + t];
    #pragma unroll
    for (int i = 0; i < 4; ++i)
      xT[Hn + t][i] = gv * c_slot[(size_t)(r0 + i) * Hn + t];
  }
  __syncthreads();

  const int jc = tid & 127;
  const int kq = tid >> 7;
  float acc[4] = {0.f, 0.f, 0.f, 0.f};
  if (jc < NSn) {
    #pragma unroll 4
    for (int k = kq * 128; k < kq * 128 + 128; ++k) {
      const float v = Ws[(size_t)k * NSn + jc];
      F4 xa; xa.v = *(const float4*)&xT[k][0];
      acc[0] += xa.f[0] * v; acc[1] += xa.f[1] * v;
      acc[2] += xa.f[2] * v; acc[3] += xa.f[3] * v;
    }
  }
  if (kq) {
    #pragma unroll
    for (int i = 0; i < 4; ++i) pp[kq - 1][i][jc] = acc[i];
  }
  __syncthreads();
  if (!kq && jc < NSn) {
    #pragma unroll
    for (int i = 0; i < 4; ++i)
      outS[(size_t)(r0 + i) * NSn + jc] =
          acc[i] + pp[0][i][jc] + pp[1][i][jc] + pp[2][i][jc];
  }
}

// ---------------------------------------------------------------------------
extern "C" void kernel_launch(void* const* d_in, const int* in_sizes, int n_in,
                              void* d_out, int out_size, void* d_ws, size_t ws_size,
                              hipStream_t stream) {
  const float* hp     = (const float*)d_in[0];
  const float* c_slot = (const float*)d_in[1];
  const float* c_inte = (const float*)d_in[2];
  const float* W_SF   = (const float*)d_in[3];
  const float* V_SF   = (const float*)d_in[4];
  const float* V1     = (const float*)d_in[5];
  const float* V2w    = (const float*)d_in[6];
  const float* V2b    = (const float*)d_in[7];
  const float* wid    = (const float*)d_in[8];
  const float* Wi     = (const float*)d_in[9];
  const float* Ws     = (const float*)d_in[10];
  float* outS = (float*)d_out;                   // B*S*NS
  float* outI = (float*)d_out + Bn * Sn * NSn;   // B*NL

  float* ws = (float*)d_ws;
  float* ZrT    = ws;                       // B*H*S (transposed, j-contig)
  float* WzT    = ZrT + Bn * Sn * Hn;       // B*H*S
  float* g2     = WzT + Bn * Sn * Hn;       // B*H
  float* alphas = g2 + Bn * Hn;             // B*S

  hipLaunchKernelGGL(k_hf, dim3(Bn * Sn / 4), dim3(512), 0, stream,
                     hp, V2w, V2b, wid, ZrT, WzT);
  for (int it = 0; it < 3; ++it) {
    hipLaunchKernelGGL(k_A, dim3(Bn), dim3(1024), 0, stream,
                       c_slot, c_inte, W_SF, V_SF, alphas, g2, it == 0 ? 1 : 0);
    hipLaunchKernelGGL(k_C, dim3(Bn * Sn / 4), dim3(512), 0, stream,
                       c_slot, V1, g2, ZrT, WzT, alphas);
  }
  hipLaunchKernelGGL(k_out1, dim3(Bn), dim3(1024), 0, stream,
                     hp, c_slot, c_inte, g2, alphas, Wi, outI);
  hipLaunchKernelGGL(k_out2, dim3(Bn * Sn / 4), dim3(512), 0, stream,
                     hp, c_slot, g2, Ws, outS);
}

// Round 4
// 178.363 us; speedup vs baseline: 1.3268x; 1.0448x over previous
//
#include <hip/hip_runtime.h>
#include <hip/hip_bf16.h>

#define Bn 16
#define Sn 128
#define Hn 256
#define NLn 22
#define NSn 122

#define K2c 2.8853900817779268f   // 2*log2(e)
#define L2Ec 1.4426950408889634f  // log2(e)

#if __has_builtin(__builtin_amdgcn_exp2f)
__device__ __forceinline__ float fexp2(float x) { return __builtin_amdgcn_exp2f(x); }
#else
__device__ __forceinline__ float fexp2(float x) { return exp2f(x); }
#endif
#if __has_builtin(__builtin_amdgcn_rcpf)
__device__ __forceinline__ float frcp(float x) { return __builtin_amdgcn_rcpf(x); }
#else
__device__ __forceinline__ float frcp(float x) { return 1.0f / x; }
#endif

union F4 { float4 v; float f[4]; };

// ---------------------------------------------------------------------------
// k_hf: hf = h @ V2_ID_w + V2_ID_b (iteration-invariant), then store
//   ZT[b][h][j] = exp2(clamp(+K2*hf[j,h]))   (j-contiguous for k_C phase 3)
// 4 rows/block, 512 threads = col(256) x k-half(2). 512 blocks.
// ---------------------------------------------------------------------------
__global__ __launch_bounds__(512) void k_hf(const float* __restrict__ hp,
                                            const float* __restrict__ V2w,
                                            const float* __restrict__ V2b,
                                            float* __restrict__ ZT) {
  __shared__ float xT[Hn][4];
  __shared__ float pp[Hn][4];
  const int tid = threadIdx.x;
  const int r0 = blockIdx.x * 4;
  const int b = r0 >> 7;          // r0 / Sn
  const int j0 = r0 & (Sn - 1);   // r0 % Sn
  if (tid < Hn) {
    #pragma unroll
    for (int i = 0; i < 4; ++i) xT[tid][i] = hp[(size_t)(r0 + i) * Hn + tid];
  }
  __syncthreads();

  const int c = tid & (Hn - 1);
  const int kh = tid >> 8;
  float acc[4] = {0.f, 0.f, 0.f, 0.f};
  #pragma unroll 4
  for (int k = kh * 128; k < kh * 128 + 128; ++k) {
    const float v = V2w[(size_t)k * Hn + c];
    F4 xa; xa.v = *(const float4*)&xT[k][0];
    acc[0] += xa.f[0] * v; acc[1] += xa.f[1] * v;
    acc[2] += xa.f[2] * v; acc[3] += xa.f[3] * v;
  }
  if (kh) {
    F4 st; st.f[0] = acc[0]; st.f[1] = acc[1]; st.f[2] = acc[2]; st.f[3] = acc[3];
    *(float4*)&pp[c][0] = st.v;
  }
  __syncthreads();
  if (!kh) {
    const float bj = V2b[c];
    #pragma unroll
    for (int i = 0; i < 4; ++i) {
      float z = K2c * (acc[i] + pp[c][i] + bj);
      z = fminf(fmaxf(z, -60.f), 60.f);
      ZT[((size_t)b * Hn + c) * Sn + j0 + i] = fexp2(z);
    }
  }
}

// ---------------------------------------------------------------------------
// k_A: 64 blocks = (b, s-quarter q), 256 threads (thread = h).
//   rL[h] = c_inte + g2prev*(sum_s c_slot*alpha)   (redundant across q)
//   m[h]  = rL @ W_SF ; em = exp2(clamp(K2*m))     (redundant across q)
//   fLq[h] = 32 - 2*sum_{s in q} rcp(1 + exp2(K2*c_slot)*em)
//   gpart[q][b][h] = fLq @ V_SF                    (partial; reduced in k_C)
// ---------------------------------------------------------------------------
__global__ __launch_bounds__(256) void k_A(const float* __restrict__ c_slot,
                                           const float* __restrict__ c_inte,
                                           const float* __restrict__ W_SF,
                                           const float* __restrict__ V_SF,
                                           const float* __restrict__ alphas,
                                           const float* __restrict__ g2,
                                           float* __restrict__ gpart,
                                           int first) {
  __shared__ float rL[Hn];
  __shared__ float fLq[Hn];
  __shared__ float aL[Sn];
  const int b = blockIdx.x >> 2;
  const int q = blockIdx.x & 3;
  const int h = threadIdx.x;

  if (!first) {
    if (h < Sn) aL[h] = alphas[b * Sn + h];
    __syncthreads();
    float rs = 0.f;
    #pragma unroll 4
    for (int s = 0; s < Sn; ++s)
      rs += c_slot[(size_t)(b * Sn + s) * Hn + h] * aL[s];
    rL[h] = c_inte[b * Hn + h] + g2[b * Hn + h] * rs;
  } else {
    rL[h] = c_inte[b * Hn + h];
  }
  __syncthreads();

  float pm = 0.f;
  #pragma unroll 4
  for (int k = 0; k < Hn; ++k)
    pm += rL[k] * W_SF[(size_t)k * Hn + h];
  float zm = K2c * pm;
  zm = fminf(fmaxf(zm, -60.f), 60.f);
  const float em = fexp2(zm);

  float pr = 0.f;
  for (int s = q * 32; s < q * 32 + 32; ++s) {
    float zc = K2c * c_slot[(size_t)(b * Sn + s) * Hn + h];
    zc = fminf(fmaxf(zc, -60.f), 60.f);
    const float e = fexp2(zc);
    pr += frcp(fmaf(e, em, 1.f));
  }
  fLq[h] = 32.f - 2.f * pr;
  __syncthreads();

  float pg = 0.f;
  #pragma unroll 4
  for (int k = 0; k < Hn; ++k)
    pg += fLq[k] * V_SF[(size_t)k * Hn + h];
  gpart[((size_t)q * Bn + b) * Hn + h] = pg;
}

// ---------------------------------------------------------------------------
// k_C: per (b, 4-row group), 512 threads = j(128) x h-quarter(4). 512 blocks.
//   phase1: g2[k] = sum_q gpart[q][b][k] (designated block writes it out);
//           x[i][k] = g2[k]*c_slot[i][k] -> LDS transposed; wid -> LDS
//   phase2: sf = x @ V1; Y = exp2(clamp(K2*sf)) -> LDS
//   phase3: acc_ij = sum_h wid[h]*rcp(1 + Y_i[h]*ZT[h][j])  (coalesced z load)
//   phase4: cross-quarter reduce; row softmax over j; emit diag alpha.
// ---------------------------------------------------------------------------
__global__ __launch_bounds__(512) void k_C(const float* __restrict__ c_slot,
                                           const float* __restrict__ V1,
                                           const float* __restrict__ gpart,
                                           const float* __restrict__ ZT,
                                           const float* __restrict__ wid,
                                           float* __restrict__ alphas,
                                           float* __restrict__ g2out) {
  __shared__ float xT[Hn][4];
  __shared__ float YT[Hn][4];
  __shared__ float pp[Hn][4];
  __shared__ float wL[Hn];
  __shared__ float red[3][4][Sn];
  __shared__ float sc[4][Sn];
  const int tid = threadIdx.x;
  const int b = blockIdx.x >> 5;
  const int i0 = (blockIdx.x & 31) * 4;

  // phase 1
  if (tid < Hn) {
    const float gv = gpart[(size_t)b * Hn + tid] +
                     gpart[((size_t)Bn + b) * Hn + tid] +
                     gpart[((size_t)2 * Bn + b) * Hn + tid] +
                     gpart[((size_t)3 * Bn + b) * Hn + tid];
    if ((blockIdx.x & 31) == 0) g2out[b * Hn + tid] = gv;
    wL[tid] = wid[tid];
    #pragma unroll
    for (int i = 0; i < 4; ++i)
      xT[tid][i] = gv * c_slot[(size_t)(b * Sn + i0 + i) * Hn + tid];
  }
  __syncthreads();

  // phase 2
  {
    const int c = tid & (Hn - 1);
    const int kh = tid >> 8;
    float acc[4] = {0.f, 0.f, 0.f, 0.f};
    #pragma unroll 4
    for (int k = kh * 128; k < kh * 128 + 128; ++k) {
      const float v = V1[(size_t)k * Hn + c];
      F4 xa; xa.v = *(const float4*)&xT[k][0];
      acc[0] += xa.f[0] * v; acc[1] += xa.f[1] * v;
      acc[2] += xa.f[2] * v; acc[3] += xa.f[3] * v;
    }
    if (kh) {
      F4 st; st.f[0] = acc[0]; st.f[1] = acc[1]; st.f[2] = acc[2]; st.f[3] = acc[3];
      *(float4*)&pp[c][0] = st.v;
    }
    __syncthreads();
    if (!kh) {
      #pragma unroll
      for (int i = 0; i < 4; ++i) {
        float z = K2c * (acc[i] + pp[c][i]);
        z = fminf(fmaxf(z, -60.f), 60.f);
        YT[c][i] = fexp2(z);
      }
    }
  }
  __syncthreads();

  // phase 3: z loads coalesced (lane = j); wid broadcast from LDS
  const int j = tid & (Sn - 1);
  const int hq = tid >> 7;
  float a4[4] = {0.f, 0.f, 0.f, 0.f};
  const float* zp = ZT + ((size_t)b * Hn + hq * 64) * Sn + j;
  #pragma unroll 4
  for (int hh = 0; hh < 64; ++hh) {
    const float z = zp[(size_t)hh * Sn];
    const float wh = wL[hq * 64 + hh];
    F4 ya; ya.v = *(const float4*)&YT[hq * 64 + hh][0];
    a4[0] += wh * frcp(fmaf(ya.f[0], z, 1.f));
    a4[1] += wh * frcp(fmaf(ya.f[1], z, 1.f));
    a4[2] += wh * frcp(fmaf(ya.f[2], z, 1.f));
    a4[3] += wh * frcp(fmaf(ya.f[3], z, 1.f));
  }
  if (hq) {
    #pragma unroll
    for (int i = 0; i < 4; ++i) red[hq - 1][i][j] = a4[i];
  }
  __syncthreads();
  if (!hq) {
    #pragma unroll
    for (int i = 0; i < 4; ++i) {
      const float tot = a4[i] + red[0][i][j] + red[1][i][j] + red[2][i][j];
      sc[i][j] = -2.f * L2Ec * tot;   // log2-scaled score (const offset dropped)
    }
  }
  __syncthreads();

  // phase 4: softmax (4 rows x 32 lanes)
  if (tid < 128) {
    const int row = tid >> 5;
    const int l5 = tid & 31;
    const float v0 = sc[row][l5];
    const float v1 = sc[row][l5 + 32];
    const float v2 = sc[row][l5 + 64];
    const float v3 = sc[row][l5 + 96];
    float mx = fmaxf(fmaxf(v0, v1), fmaxf(v2, v3));
    #pragma unroll
    for (int o = 16; o >= 1; o >>= 1) mx = fmaxf(mx, __shfl_xor(mx, o, 32));
    float sm = fexp2(v0 - mx) + fexp2(v1 - mx) + fexp2(v2 - mx) + fexp2(v3 - mx);
    #pragma unroll
    for (int o = 16; o >= 1; o >>= 1) sm += __shfl_xor(sm, o, 32);
    if (l5 == 0) {
      const int ig = i0 + row;
      const float d = sc[row][ig];
      alphas[b * Sn + ig] = fexp2(d - mx) * frcp(sm);
    }
  }
}

// ---------------------------------------------------------------------------
// k_out1: intent head (uses final g2 written by k_C designated blocks).
// ---------------------------------------------------------------------------
__global__ __launch_bounds__(1024) void k_out1(const float* __restrict__ hp,
                                               const float* __restrict__ c_slot,
                                               const float* __restrict__ c_inte,
                                               const float* __restrict__ g2,
                                               const float* __restrict__ alphas,
                                               const float* __restrict__ Wi,
                                               float* __restrict__ outI) {
  __shared__ float aL[Sn];
  __shared__ float cv[2 * Hn];
  __shared__ float pt[4][Hn];
  __shared__ float ip[NLn][16];
  const int b = blockIdx.x;
  const int tid = threadIdx.x;
  if (tid < Sn) aL[tid] = alphas[b * Sn + tid];
  __syncthreads();
  const int h = tid & (Hn - 1);
  const int q = tid >> 8;
  float ps = 0.f;
  for (int s = q * 32; s < q * 32 + 32; ++s)
    ps += c_slot[(size_t)(b * Sn + s) * Hn + h] * aL[s];
  pt[q][h] = ps;
  __syncthreads();
  if (q == 0) {
    cv[h] = c_inte[b * Hn + h] + g2[b * Hn + h] * (pt[0][h] + pt[1][h] + pt[2][h] + pt[3][h]);
    cv[Hn + h] = hp[(size_t)(b * Sn + Sn - 1) * Hn + h];
  }
  __syncthreads();
  if (tid < NLn * 16) {
    const int l = tid >> 4, c = tid & 15;
    float p = 0.f;
    for (int k = c * 32; k < c * 32 + 32; ++k) p += cv[k] * Wi[k * NLn + l];
    ip[l][c] = p;
  }
  __syncthreads();
  if (tid < NLn) {
    float t = 0.f;
    #pragma unroll
    for (int c = 0; c < 16; ++c) t += ip[tid][c];
    outI[b * NLn + tid] = t;
  }
}

// ---------------------------------------------------------------------------
// k_out2: slot head (unchanged).
// ---------------------------------------------------------------------------
__global__ __launch_bounds__(512) void k_out2(const float* __restrict__ hp,
                                              const float* __restrict__ c_slot,
                                              const float* __restrict__ g2,
                                              const float* __restrict__ Ws,
                                              float* __restrict__ outS) {
  __shared__ float xT[2 * Hn][4];
  __shared__ float pp[3][4][128];
  const int tid = threadIdx.x;
  const int r0 = blockIdx.x * 4;
  const int b = r0 / Sn;
  if (tid < Hn) {
    #pragma unroll
    for (int i = 0; i < 4; ++i)
      xT[tid][i] = hp[(size_t)(r0 + i) * Hn + tid];
  } else {
    const int t = tid - Hn;
    const float gv = g2[b * Hn + t];
    #pragma unroll
    for (int i = 0; i < 4; ++i)
      xT[Hn + t][i] = gv * c_slot[(size_t)(r0 + i) * Hn + t];
  }
  __syncthreads();

  const int jc = tid & 127;
  const int kq = tid >> 7;
  float acc[4] = {0.f, 0.f, 0.f, 0.f};
  if (jc < NSn) {
    #pragma unroll 4
    for (int k = kq * 128; k < kq * 128 + 128; ++k) {
      const float v = Ws[(size_t)k * NSn + jc];
      F4 xa; xa.v = *(const float4*)&xT[k][0];
      acc[0] += xa.f[0] * v; acc[1] += xa.f[1] * v;
      acc[2] += xa.f[2] * v; acc[3] += xa.f[3] * v;
    }
  }
  if (kq) {
    #pragma unroll
    for (int i = 0; i < 4; ++i) pp[kq - 1][i][jc] = acc[i];
  }
  __syncthreads();
  if (!kq && jc < NSn) {
    #pragma unroll
    for (int i = 0; i < 4; ++i)
      outS[(size_t)(r0 + i) * NSn + jc] =
          acc[i] + pp[0][i][jc] + pp[1][i][jc] + pp[2][i][jc];
  }
}

// ---------------------------------------------------------------------------
extern "C" void kernel_launch(void* const* d_in, const int* in_sizes, int n_in,
                              void* d_out, int out_size, void* d_ws, size_t ws_size,
                              hipStream_t stream) {
  const float* hp     = (const float*)d_in[0];
  const float* c_slot = (const float*)d_in[1];
  const float* c_inte = (const float*)d_in[2];
  const float* W_SF   = (const float*)d_in[3];
  const float* V_SF   = (const float*)d_in[4];
  const float* V1     = (const float*)d_in[5];
  const float* V2w    = (const float*)d_in[6];
  const float* V2b    = (const float*)d_in[7];
  const float* wid    = (const float*)d_in[8];
  const float* Wi     = (const float*)d_in[9];
  const float* Ws     = (const float*)d_in[10];
  float* outS = (float*)d_out;                   // B*S*NS
  float* outI = (float*)d_out + Bn * Sn * NSn;   // B*NL

  float* ws = (float*)d_ws;
  float* ZT     = ws;                       // B*H*S (transposed, j-contig)
  float* gpart  = ZT + Bn * Sn * Hn;        // 4*B*H
  float* g2     = gpart + 4 * Bn * Hn;      // B*H
  float* alphas = g2 + Bn * Hn;             // B*S

  hipLaunchKernelGGL(k_hf, dim3(Bn * Sn / 4), dim3(512), 0, stream,
                     hp, V2w, V2b, ZT);
  for (int it = 0; it < 3; ++it) {
    hipLaunchKernelGGL(k_A, dim3(Bn * 4), dim3(256), 0, stream,
                       c_slot, c_inte, W_SF, V_SF, alphas, g2, gpart, it == 0 ? 1 : 0);
    hipLaunchKernelGGL(k_C, dim3(Bn * Sn / 4), dim3(512), 0, stream,
                       c_slot, V1, gpart, ZT, wid, alphas, g2);
  }
  hipLaunchKernelGGL(k_out1, dim3(Bn), dim3(1024), 0, stream,
                     hp, c_slot, c_inte, g2, alphas, Wi, outI);
  hipLaunchKernelGGL(k_out2, dim3(Bn * Sn / 4), dim3(512), 0, stream,
                     hp, c_slot, g2, Ws, outS);
}

// Round 5
// 125.899 us; speedup vs baseline: 1.8797x; 1.4167x over previous
//
#include <hip/hip_runtime.h>
#include <hip/hip_bf16.h>

#define Bn 16
#define Sn 128
#define Hn 256
#define NLn 22
#define NSn 122

#define K2c 2.8853900817779268f   // 2*log2(e)
#define L2Ec 1.4426950408889634f  // log2(e)

#if __has_builtin(__builtin_amdgcn_exp2f)
__device__ __forceinline__ float fexp2(float x) { return __builtin_amdgcn_exp2f(x); }
#else
__device__ __forceinline__ float fexp2(float x) { return exp2f(x); }
#endif
#if __has_builtin(__builtin_amdgcn_rcpf)
__device__ __forceinline__ float frcp(float x) { return __builtin_amdgcn_rcpf(x); }
#else
__device__ __forceinline__ float frcp(float x) { return 1.0f / x; }
#endif

union F4 { float4 v; float f[4]; };

// ---------------------------------------------------------------------------
// k_hf: hf = h @ V2_ID_w + V2_ID_b (iteration-invariant), then store
//   ZT[b][h][j] = exp2(clamp(+K2*hf[j,h]))   (j-contiguous for k_C phase 3)
// 4 rows/block, 512 threads = col(256) x k-half(2). 512 blocks.
// ---------------------------------------------------------------------------
__global__ __launch_bounds__(512) void k_hf(const float* __restrict__ hp,
                                            const float* __restrict__ V2w,
                                            const float* __restrict__ V2b,
                                            float* __restrict__ ZT) {
  __shared__ float xT[Hn][4];
  __shared__ float pp[Hn][4];
  const int tid = threadIdx.x;
  const int r0 = blockIdx.x * 4;
  const int b = r0 >> 7;          // r0 / Sn
  const int j0 = r0 & (Sn - 1);   // r0 % Sn
  if (tid < Hn) {
    #pragma unroll
    for (int i = 0; i < 4; ++i) xT[tid][i] = hp[(size_t)(r0 + i) * Hn + tid];
  }
  __syncthreads();

  const int c = tid & (Hn - 1);
  const int kh = tid >> 8;
  float acc[4] = {0.f, 0.f, 0.f, 0.f};
  #pragma unroll 4
  for (int k = kh * 128; k < kh * 128 + 128; ++k) {
    const float v = V2w[(size_t)k * Hn + c];
    F4 xa; xa.v = *(const float4*)&xT[k][0];
    acc[0] += xa.f[0] * v; acc[1] += xa.f[1] * v;
    acc[2] += xa.f[2] * v; acc[3] += xa.f[3] * v;
  }
  if (kh) {
    F4 st; st.f[0] = acc[0]; st.f[1] = acc[1]; st.f[2] = acc[2]; st.f[3] = acc[3];
    *(float4*)&pp[c][0] = st.v;
  }
  __syncthreads();
  if (!kh) {
    const float bj = V2b[c];
    #pragma unroll
    for (int i = 0; i < 4; ++i) {
      float z = K2c * (acc[i] + pp[c][i] + bj);
      z = fminf(fmaxf(z, -60.f), 60.f);
      ZT[((size_t)b * Hn + c) * Sn + j0 + i] = fexp2(z);
    }
  }
}

// ---------------------------------------------------------------------------
// k_A: 64 blocks = (b, s-quarter q), 1024 threads = h(256) x kq(4).
// Every reduction loop is 4-way split over kq (LDS cross-reduce) to cut the
// per-thread serial load chain: rs 32, m 64, f 8, g 64 loads/thread.
//   rL[h] = c_inte + g2prev*(sum_s c_slot*alpha)   (redundant across q)
//   m[h]  = rL @ W_SF ; em = exp2(clamp(K2*m))     (redundant across q)
//   fLq[h] = 32 - 2*sum_{s in q} rcp(1 + exp2(K2*c_slot)*em)
//   gpart[q][b][h] = fLq @ V_SF                    (partial; reduced in k_C)
// ---------------------------------------------------------------------------
__global__ __launch_bounds__(1024) void k_A(const float* __restrict__ c_slot,
                                            const float* __restrict__ c_inte,
                                            const float* __restrict__ W_SF,
                                            const float* __restrict__ V_SF,
                                            const float* __restrict__ alphas,
                                            const float* __restrict__ g2,
                                            float* __restrict__ gpart,
                                            int first) {
  __shared__ float rL[Hn];
  __shared__ float fLq[Hn];
  __shared__ float aL[Sn];
  __shared__ float pt[4][Hn];
  const int b = blockIdx.x >> 2;
  const int q = blockIdx.x & 3;
  const int tid = threadIdx.x;
  const int h = tid & (Hn - 1);
  const int kq = tid >> 8;

  if (!first) {
    if (tid < Sn) aL[tid] = alphas[b * Sn + tid];
    __syncthreads();
    float ps = 0.f;
    #pragma unroll 8
    for (int s = kq * 32; s < kq * 32 + 32; ++s)
      ps += c_slot[(size_t)(b * Sn + s) * Hn + h] * aL[s];
    pt[kq][h] = ps;
    __syncthreads();
    if (kq == 0)
      rL[h] = c_inte[b * Hn + h] +
              g2[b * Hn + h] * (pt[0][h] + pt[1][h] + pt[2][h] + pt[3][h]);
  } else {
    if (kq == 0) rL[h] = c_inte[b * Hn + h];
  }
  __syncthreads();

  // m[h] = rL @ W_SF, 4-way k-split
  float pm = 0.f;
  #pragma unroll 8
  for (int k = kq * 64; k < kq * 64 + 64; ++k)
    pm += rL[k] * W_SF[(size_t)k * Hn + h];
  __syncthreads();               // protect pt from rs-phase reads
  pt[kq][h] = pm;
  __syncthreads();
  const float m = pt[0][h] + pt[1][h] + pt[2][h] + pt[3][h];
  float zm = K2c * m;
  zm = fminf(fmaxf(zm, -60.f), 60.f);
  const float em = fexp2(zm);

  // f partial: 8 s-values per thread
  float pr = 0.f;
  #pragma unroll
  for (int s = q * 32 + kq * 8; s < q * 32 + kq * 8 + 8; ++s) {
    float zc = K2c * c_slot[(size_t)(b * Sn + s) * Hn + h];
    zc = fminf(fmaxf(zc, -60.f), 60.f);
    pr += frcp(fmaf(fexp2(zc), em, 1.f));
  }
  __syncthreads();
  pt[kq][h] = pr;
  __syncthreads();
  if (kq == 0)
    fLq[h] = 32.f - 2.f * (pt[0][h] + pt[1][h] + pt[2][h] + pt[3][h]);
  __syncthreads();

  // gpart[h] = fLq @ V_SF, 4-way k-split
  float pg = 0.f;
  #pragma unroll 8
  for (int k = kq * 64; k < kq * 64 + 64; ++k)
    pg += fLq[k] * V_SF[(size_t)k * Hn + h];
  __syncthreads();
  pt[kq][h] = pg;
  __syncthreads();
  if (kq == 0)
    gpart[((size_t)q * Bn + b) * Hn + h] =
        pt[0][h] + pt[1][h] + pt[2][h] + pt[3][h];
}

// ---------------------------------------------------------------------------
// k_C: per (b, 4-row group), 512 threads = j(128) x h-quarter(4). 512 blocks.
//   phase1: g2[k] = sum_q gpart[q][b][k] (designated block writes it out);
//           x[i][k] = g2[k]*c_slot[i][k] -> LDS transposed; wid -> LDS
//   phase2: sf = x @ V1; Y = exp2(clamp(K2*sf)) -> LDS
//   phase3: acc_ij = sum_h wid[h]*rcp(1 + Y_i[h]*ZT[h][j])  (coalesced z load)
//   phase4: cross-quarter reduce; row softmax over j; emit diag alpha.
// ---------------------------------------------------------------------------
__global__ __launch_bounds__(512) void k_C(const float* __restrict__ c_slot,
                                           const float* __restrict__ V1,
                                           const float* __restrict__ gpart,
                                           const float* __restrict__ ZT,
                                           const float* __restrict__ wid,
                                           float* __restrict__ alphas,
                                           float* __restrict__ g2out) {
  __shared__ float xT[Hn][4];
  __shared__ float YT[Hn][4];
  __shared__ float pp[Hn][4];
  __shared__ float wL[Hn];
  __shared__ float red[3][4][Sn];
  __shared__ float sc[4][Sn];
  const int tid = threadIdx.x;
  const int b = blockIdx.x >> 5;
  const int i0 = (blockIdx.x & 31) * 4;

  // phase 1
  if (tid < Hn) {
    const float gv = gpart[(size_t)b * Hn + tid] +
                     gpart[((size_t)Bn + b) * Hn + tid] +
                     gpart[((size_t)2 * Bn + b) * Hn + tid] +
                     gpart[((size_t)3 * Bn + b) * Hn + tid];
    if ((blockIdx.x & 31) == 0) g2out[b * Hn + tid] = gv;
    wL[tid] = wid[tid];
    #pragma unroll
    for (int i = 0; i < 4; ++i)
      xT[tid][i] = gv * c_slot[(size_t)(b * Sn + i0 + i) * Hn + tid];
  }
  __syncthreads();

  // phase 2
  {
    const int c = tid & (Hn - 1);
    const int kh = tid >> 8;
    float acc[4] = {0.f, 0.f, 0.f, 0.f};
    #pragma unroll 4
    for (int k = kh * 128; k < kh * 128 + 128; ++k) {
      const float v = V1[(size_t)k * Hn + c];
      F4 xa; xa.v = *(const float4*)&xT[k][0];
      acc[0] += xa.f[0] * v; acc[1] += xa.f[1] * v;
      acc[2] += xa.f[2] * v; acc[3] += xa.f[3] * v;
    }
    if (kh) {
      F4 st; st.f[0] = acc[0]; st.f[1] = acc[1]; st.f[2] = acc[2]; st.f[3] = acc[3];
      *(float4*)&pp[c][0] = st.v;
    }
    __syncthreads();
    if (!kh) {
      #pragma unroll
      for (int i = 0; i < 4; ++i) {
        float z = K2c * (acc[i] + pp[c][i]);
        z = fminf(fmaxf(z, -60.f), 60.f);
        YT[c][i] = fexp2(z);
      }
    }
  }
  __syncthreads();

  // phase 3: z loads coalesced (lane = j); wid broadcast from LDS
  const int j = tid & (Sn - 1);
  const int hq = tid >> 7;
  float a4[4] = {0.f, 0.f, 0.f, 0.f};
  const float* zp = ZT + ((size_t)b * Hn + hq * 64) * Sn + j;
  #pragma unroll 4
  for (int hh = 0; hh < 64; ++hh) {
    const float z = zp[(size_t)hh * Sn];
    const float wh = wL[hq * 64 + hh];
    F4 ya; ya.v = *(const float4*)&YT[hq * 64 + hh][0];
    a4[0] += wh * frcp(fmaf(ya.f[0], z, 1.f));
    a4[1] += wh * frcp(fmaf(ya.f[1], z, 1.f));
    a4[2] += wh * frcp(fmaf(ya.f[2], z, 1.f));
    a4[3] += wh * frcp(fmaf(ya.f[3], z, 1.f));
  }
  if (hq) {
    #pragma unroll
    for (int i = 0; i < 4; ++i) red[hq - 1][i][j] = a4[i];
  }
  __syncthreads();
  if (!hq) {
    #pragma unroll
    for (int i = 0; i < 4; ++i) {
      const float tot = a4[i] + red[0][i][j] + red[1][i][j] + red[2][i][j];
      sc[i][j] = -2.f * L2Ec * tot;   // log2-scaled score (const offset dropped)
    }
  }
  __syncthreads();

  // phase 4: softmax (4 rows x 32 lanes)
  if (tid < 128) {
    const int row = tid >> 5;
    const int l5 = tid & 31;
    const float v0 = sc[row][l5];
    const float v1 = sc[row][l5 + 32];
    const float v2 = sc[row][l5 + 64];
    const float v3 = sc[row][l5 + 96];
    float mx = fmaxf(fmaxf(v0, v1), fmaxf(v2, v3));
    #pragma unroll
    for (int o = 16; o >= 1; o >>= 1) mx = fmaxf(mx, __shfl_xor(mx, o, 32));
    float sm = fexp2(v0 - mx) + fexp2(v1 - mx) + fexp2(v2 - mx) + fexp2(v3 - mx);
    #pragma unroll
    for (int o = 16; o >= 1; o >>= 1) sm += __shfl_xor(sm, o, 32);
    if (l5 == 0) {
      const int ig = i0 + row;
      const float d = sc[row][ig];
      alphas[b * Sn + ig] = fexp2(d - mx) * frcp(sm);
    }
  }
}

// ---------------------------------------------------------------------------
// k_out1: intent head (uses final g2 written by k_C designated blocks).
// ---------------------------------------------------------------------------
__global__ __launch_bounds__(1024) void k_out1(const float* __restrict__ hp,
                                               const float* __restrict__ c_slot,
                                               const float* __restrict__ c_inte,
                                               const float* __restrict__ g2,
                                               const float* __restrict__ alphas,
                                               const float* __restrict__ Wi,
                                               float* __restrict__ outI) {
  __shared__ float aL[Sn];
  __shared__ float cv[2 * Hn];
  __shared__ float pt[4][Hn];
  __shared__ float ip[NLn][16];
  const int b = blockIdx.x;
  const int tid = threadIdx.x;
  if (tid < Sn) aL[tid] = alphas[b * Sn + tid];
  __syncthreads();
  const int h = tid & (Hn - 1);
  const int q = tid >> 8;
  float ps = 0.f;
  for (int s = q * 32; s < q * 32 + 32; ++s)
    ps += c_slot[(size_t)(b * Sn + s) * Hn + h] * aL[s];
  pt[q][h] = ps;
  __syncthreads();
  if (q == 0) {
    cv[h] = c_inte[b * Hn + h] + g2[b * Hn + h] * (pt[0][h] + pt[1][h] + pt[2][h] + pt[3][h]);
    cv[Hn + h] = hp[(size_t)(b * Sn + Sn - 1) * Hn + h];
  }
  __syncthreads();
  if (tid < NLn * 16) {
    const int l = tid >> 4, c = tid & 15;
    float p = 0.f;
    for (int k = c * 32; k < c * 32 + 32; ++k) p += cv[k] * Wi[k * NLn + l];
    ip[l][c] = p;
  }
  __syncthreads();
  if (tid < NLn) {
    float t = 0.f;
    #pragma unroll
    for (int c = 0; c < 16; ++c) t += ip[tid][c];
    outI[b * NLn + tid] = t;
  }
}

// ---------------------------------------------------------------------------
// k_out2: slot head (unchanged).
// ---------------------------------------------------------------------------
__global__ __launch_bounds__(512) void k_out2(const float* __restrict__ hp,
                                              const float* __restrict__ c_slot,
                                              const float* __restrict__ g2,
                                              const float* __restrict__ Ws,
                                              float* __restrict__ outS) {
  __shared__ float xT[2 * Hn][4];
  __shared__ float pp[3][4][128];
  const int tid = threadIdx.x;
  const int r0 = blockIdx.x * 4;
  const int b = r0 / Sn;
  if (tid < Hn) {
    #pragma unroll
    for (int i = 0; i < 4; ++i)
      xT[tid][i] = hp[(size_t)(r0 + i) * Hn + tid];
  } else {
    const int t = tid - Hn;
    const float gv = g2[b * Hn + t];
    #pragma unroll
    for (int i = 0; i < 4; ++i)
      xT[Hn + t][i] = gv * c_slot[(size_t)(r0 + i) * Hn + t];
  }
  __syncthreads();

  const int jc = tid & 127;
  const int kq = tid >> 7;
  float acc[4] = {0.f, 0.f, 0.f, 0.f};
  if (jc < NSn) {
    #pragma unroll 4
    for (int k = kq * 128; k < kq * 128 + 128; ++k) {
      const float v = Ws[(size_t)k * NSn + jc];
      F4 xa; xa.v = *(const float4*)&xT[k][0];
      acc[0] += xa.f[0] * v; acc[1] += xa.f[1] * v;
      acc[2] += xa.f[2] * v; acc[3] += xa.f[3] * v;
    }
  }
  if (kq) {
    #pragma unroll
    for (int i = 0; i < 4; ++i) pp[kq - 1][i][jc] = acc[i];
  }
  __syncthreads();
  if (!kq && jc < NSn) {
    #pragma unroll
    for (int i = 0; i < 4; ++i)
      outS[(size_t)(r0 + i) * NSn + jc] =
          acc[i] + pp[0][i][jc] + pp[1][i][jc] + pp[2][i][jc];
  }
}

// ---------------------------------------------------------------------------
extern "C" void kernel_launch(void* const* d_in, const int* in_sizes, int n_in,
                              void* d_out, int out_size, void* d_ws, size_t ws_size,
                              hipStream_t stream) {
  const float* hp     = (const float*)d_in[0];
  const float* c_slot = (const float*)d_in[1];
  const float* c_inte = (const float*)d_in[2];
  const float* W_SF   = (const float*)d_in[3];
  const float* V_SF   = (const float*)d_in[4];
  const float* V1     = (const float*)d_in[5];
  const float* V2w    = (const float*)d_in[6];
  const float* V2b    = (const float*)d_in[7];
  const float* wid    = (const float*)d_in[8];
  const float* Wi     = (const float*)d_in[9];
  const float* Ws     = (const float*)d_in[10];
  float* outS = (float*)d_out;                   // B*S*NS
  float* outI = (float*)d_out + Bn * Sn * NSn;   // B*NL

  float* ws = (float*)d_ws;
  float* ZT     = ws;                       // B*H*S (transposed, j-contig)
  float* gpart  = ZT + Bn * Sn * Hn;        // 4*B*H
  float* g2     = gpart + 4 * Bn * Hn;      // B*H
  float* alphas = g2 + Bn * Hn;             // B*S

  hipLaunchKernelGGL(k_hf, dim3(Bn * Sn / 4), dim3(512), 0, stream,
                     hp, V2w, V2b, ZT);
  for (int it = 0; it < 3; ++it) {
    hipLaunchKernelGGL(k_A, dim3(Bn * 4), dim3(1024), 0, stream,
                       c_slot, c_inte, W_SF, V_SF, alphas, g2, gpart, it == 0 ? 1 : 0);
    hipLaunchKernelGGL(k_C, dim3(Bn * Sn / 4), dim3(512), 0, stream,
                       c_slot, V1, gpart, ZT, wid, alphas, g2);
  }
  hipLaunchKernelGGL(k_out1, dim3(Bn), dim3(1024), 0, stream,
                     hp, c_slot, c_inte, g2, alphas, Wi, outI);
  hipLaunchKernelGGL(k_out2, dim3(Bn * Sn / 4), dim3(512), 0, stream,
                     hp, c_slot, g2, Ws, outS);
}